// Round 1
// baseline (287.036 us; speedup 1.0000x reference)
//
#include <hip/hip_runtime.h>
#include <hip/hip_bf16.h>

typedef unsigned short u16;
typedef unsigned int u32;
typedef __attribute__((ext_vector_type(8))) __bf16 bf16x8;
typedef __attribute__((ext_vector_type(4))) float f32x4;
typedef __attribute__((ext_vector_type(4))) u16 u16x4;

__device__ __forceinline__ u16 f2bf(float f) {
  u32 u = __builtin_bit_cast(u32, f);
  u32 r = (u + 0x7fffu + ((u >> 16) & 1u)) >> 16;
  return (u16)r;
}
__device__ __forceinline__ float bf2f(u16 h) {
  return __builtin_bit_cast(float, (u32)h << 16);
}

__device__ __forceinline__ void gload_lds16(const void* g, void* l) {
  __builtin_amdgcn_global_load_lds((const __attribute__((address_space(1))) void*)g,
                                   (__attribute__((address_space(3))) void*)l, 16, 0, 0);
}

// ---------------- fp32 -> bf16 convert (x) ----------------
__global__ __launch_bounds__(256) void cvt_kernel(const float* __restrict__ in, u16* __restrict__ out) {
  const int i = (blockIdx.x * 256 + threadIdx.x) * 4;
  const float4 v = *(const float4*)(in + i);
  u16x4 r = {f2bf(v.x), f2bf(v.y), f2bf(v.z), f2bf(v.w)};
  *(u16x4*)(out + i) = r;
}

// ---------------- transpose + convert weights: w[K][N] f32 -> wt[N][K] bf16 ----------------
__global__ __launch_bounds__(256) void transpose_w(const float* __restrict__ w, u16* __restrict__ wt,
                                                   int K, int N) {
  __shared__ u16 tile[64][65];
  const int n0 = blockIdx.x * 64, k0 = blockIdx.y * 64;
  const int tid = threadIdx.x;
#pragma unroll
  for (int it = 0; it < 16; ++it) {
    const int idx = it * 256 + tid;
    const int r = idx >> 6, c = idx & 63;
    tile[r][c] = f2bf(w[(size_t)(k0 + r) * N + n0 + c]);
  }
  __syncthreads();
#pragma unroll
  for (int it = 0; it < 16; ++it) {
    const int idx = it * 256 + tid;
    const int r2 = idx >> 6, c2 = idx & 63;
    wt[(size_t)(n0 + r2) * K + k0 + c2] = tile[c2][r2];
  }
}

// ---------------- bf16 GEMM: C[M][N] = A[M][K] * Bt[N][K]^T  (m97 structure) ----------------
template <int OUT_F32>
__global__ __launch_bounds__(256) void gemm_bt(const u16* __restrict__ A, const u16* __restrict__ Bt,
                                               void* __restrict__ Cout, int M, int N, int K) {
  __shared__ u16 As[128 * 32];
  __shared__ u16 Bs[128 * 32];
  const int tid = threadIdx.x;
  const int wave = tid >> 6;
  const int lane = tid & 63;
  const int la = lane & 15, lb = lane >> 4;
  const int m0 = blockIdx.x * 128, n0 = blockIdx.y * 128;
  const int wr = (wave >> 1) * 64, wc = (wave & 1) * 64;
  const int srow = lane >> 2;       // 0..15
  const int scol = (lane & 3) * 8;  // 0,8,16,24
  const int c0 = wave * 2;
  f32x4 acc[4][4] = {};
  for (int k0 = 0; k0 < K; k0 += 32) {
#pragma unroll
    for (int c2 = 0; c2 < 2; ++c2) {
      const int c = c0 + c2;
      const int row = c * 16 + srow;
      gload_lds16(A + (size_t)(m0 + row) * K + k0 + scol, As + c * 512);
      gload_lds16(Bt + (size_t)(n0 + row) * K + k0 + scol, Bs + c * 512);
    }
    __syncthreads();
    bf16x8 af[4], bfr[4];
#pragma unroll
    for (int m = 0; m < 4; ++m) af[m] = *(const bf16x8*)&As[(wr + m * 16 + la) * 32 + lb * 8];
#pragma unroll
    for (int n = 0; n < 4; ++n) bfr[n] = *(const bf16x8*)&Bs[(wc + n * 16 + la) * 32 + lb * 8];
#pragma unroll
    for (int m = 0; m < 4; ++m)
#pragma unroll
      for (int n = 0; n < 4; ++n)
        acc[m][n] = __builtin_amdgcn_mfma_f32_16x16x32_bf16(af[m], bfr[n], acc[m][n], 0, 0, 0);
    __syncthreads();
  }
#pragma unroll
  for (int m = 0; m < 4; ++m)
#pragma unroll
    for (int n = 0; n < 4; ++n)
#pragma unroll
      for (int j = 0; j < 4; ++j) {
        const int row = m0 + wr + m * 16 + lb * 4 + j;
        const int col = n0 + wc + n * 16 + la;
        if (OUT_F32)
          ((float*)Cout)[(size_t)row * N + col] = acc[m][n][j];
        else
          ((u16*)Cout)[(size_t)row * N + col] = f2bf(acc[m][n][j]);
      }
}

// ---------------- RoPE + head reshape + V transpose ----------------
// qkv[b][t][3072] bf16 -> q[bh][t][64] (roped, *0.125), k[bh][t][64] (roped), vt[bh][64][2048]
__global__ __launch_bounds__(256) void rope_kernel(const u16* __restrict__ QKV, u16* __restrict__ Q,
                                                   u16* __restrict__ K, u16* __restrict__ Vt) {
  const int tt = blockIdx.x * 64;
  const int bh = blockIdx.y;
  const int b = bh >> 4, h = bh & 15;
  const int tid = threadIdx.x;
  __shared__ u16 vtile[64][65];
  const float NEG = -0.41524101186f;  // -log2(10000)/32
#pragma unroll
  for (int it = 0; it < 8; ++it) {
    const int idx = it * 256 + tid;
    const int tl = idx >> 5, i = idx & 31;
    const int t = tt + tl;
    const int d0 = 2 * i;
    const int j0 = d0 & 31, j1 = (d0 + 1) & 31;
    const float a0 = (float)t * exp2f(NEG * (float)j0);
    const float a1 = (float)t * exp2f(NEG * (float)j1);
    float s0, c0v, s1, c1v;
    sincosf(a0, &s0, &c0v);
    sincosf(a1, &s1, &c1v);
    const size_t base = ((size_t)(b * 2048 + t)) * 3072 + h * 64 + d0;
    const size_t ob = ((size_t)bh * 2048 + t) * 64 + d0;
    {
      const float x0 = bf2f(QKV[base]), x1 = bf2f(QKV[base + 1]);
      Q[ob] = f2bf((x0 * c0v - x1 * s0) * 0.125f);
      Q[ob + 1] = f2bf((x1 * c1v + x0 * s1) * 0.125f);
    }
    {
      const float x0 = bf2f(QKV[base + 1024]), x1 = bf2f(QKV[base + 1025]);
      K[ob] = f2bf(x0 * c0v - x1 * s0);
      K[ob + 1] = f2bf(x1 * c1v + x0 * s1);
    }
  }
  // V transpose through LDS
#pragma unroll
  for (int it = 0; it < 8; ++it) {
    const int idx = it * 256 + tid;
    const int tl = idx >> 5, d0 = (idx & 31) * 2;
    const size_t base = ((size_t)(b * 2048 + tt + tl)) * 3072 + 2048 + h * 64 + d0;
    vtile[tl][d0] = QKV[base];
    vtile[tl][d0 + 1] = QKV[base + 1];
  }
  __syncthreads();
#pragma unroll
  for (int it = 0; it < 8; ++it) {
    const int idx = it * 256 + tid;
    const int dl = idx >> 5, tp = (idx & 31) * 2;
    const u32 val = (u32)vtile[tp][dl] | ((u32)vtile[tp + 1][dl] << 16);
    *(u32*)(Vt + ((size_t)bh * 64 + dl) * 2048 + tt + tp) = val;
  }
}

// ---------------- flash attention (causal), QBLK=128 (32/wave), KBLK=64 ----------------
__global__ __launch_bounds__(256) void attn_kernel(const u16* __restrict__ Q, const u16* __restrict__ K,
                                                   const u16* __restrict__ Vt, u16* __restrict__ Y) {
  const int qi = blockIdx.x;
  const int bh = blockIdx.y;
  const int b = bh >> 4, h = bh & 15;
  const int wave = threadIdx.x >> 6, lane = threadIdx.x & 63;
  const int la = lane & 15, lb = lane >> 4;
  __shared__ u16 Plds[4][32 * 64];
  u16* pw = &Plds[wave][0];
  const size_t plane = (size_t)bh * (2048 * 64);
  const int q0 = qi * 128 + wave * 32;
  bf16x8 qf[2][2];
#pragma unroll
  for (int m = 0; m < 2; ++m)
#pragma unroll
    for (int s = 0; s < 2; ++s)
      qf[m][s] = *(const bf16x8*)(Q + plane + (size_t)(q0 + m * 16 + la) * 64 + s * 32 + lb * 8);
  f32x4 o[2][4] = {};
  float mrow[2][4], lrow[2][4];
#pragma unroll
  for (int m = 0; m < 2; ++m)
#pragma unroll
    for (int j = 0; j < 4; ++j) {
      mrow[m][j] = -3.0e38f;
      lrow[m][j] = 0.f;
    }
  const int ntiles = ((q0 + 31) >> 6) + 1;
  for (int kt = 0; kt < ntiles; ++kt) {
    f32x4 sa[2][4] = {};
#pragma unroll
    for (int s = 0; s < 2; ++s) {
      bf16x8 kf[4];
#pragma unroll
      for (int n = 0; n < 4; ++n)
        kf[n] = *(const bf16x8*)(K + plane + (size_t)(kt * 64 + n * 16 + la) * 64 + s * 32 + lb * 8);
#pragma unroll
      for (int m = 0; m < 2; ++m)
#pragma unroll
        for (int n = 0; n < 4; ++n)
          sa[m][n] = __builtin_amdgcn_mfma_f32_16x16x32_bf16(qf[m][s], kf[n], sa[m][n], 0, 0, 0);
    }
    if (kt * 64 + 63 > q0) {  // diagonal region: apply causal mask
#pragma unroll
      for (int m = 0; m < 2; ++m)
#pragma unroll
        for (int n = 0; n < 4; ++n)
#pragma unroll
          for (int j = 0; j < 4; ++j) {
            const int row = q0 + m * 16 + lb * 4 + j;
            const int col = kt * 64 + n * 16 + la;
            if (col > row) sa[m][n][j] = -3.0e38f;
          }
    }
#pragma unroll
    for (int m = 0; m < 2; ++m) {
#pragma unroll
      for (int j = 0; j < 4; ++j) {
        float v = fmaxf(fmaxf(sa[m][0][j], sa[m][1][j]), fmaxf(sa[m][2][j], sa[m][3][j]));
#pragma unroll
        for (int off = 1; off < 16; off <<= 1) v = fmaxf(v, __shfl_xor(v, off));
        const float mn = fmaxf(mrow[m][j], v);
        const float al = expf(mrow[m][j] - mn);
        float sum = 0.f;
#pragma unroll
        for (int n = 0; n < 4; ++n) {
          const float pv = expf(sa[m][n][j] - mn);
          sum += pv;
          pw[(m * 16 + lb * 4 + j) * 64 + n * 16 + la] = f2bf(pv);
        }
#pragma unroll
        for (int off = 1; off < 16; off <<= 1) sum += __shfl_xor(sum, off);
        lrow[m][j] = lrow[m][j] * al + sum;
        mrow[m][j] = mn;
#pragma unroll
        for (int n = 0; n < 4; ++n) o[m][n][j] *= al;
      }
    }
#pragma unroll
    for (int s = 0; s < 2; ++s) {
      bf16x8 pf[2];
#pragma unroll
      for (int m = 0; m < 2; ++m) pf[m] = *(const bf16x8*)&pw[(m * 16 + la) * 64 + s * 32 + lb * 8];
#pragma unroll
      for (int n = 0; n < 4; ++n) {
        bf16x8 vf = *(const bf16x8*)(Vt + plane + (size_t)(n * 16 + la) * 2048 + kt * 64 + s * 32 + lb * 8);
#pragma unroll
        for (int m = 0; m < 2; ++m)
          o[m][n] = __builtin_amdgcn_mfma_f32_16x16x32_bf16(pf[m], vf, o[m][n], 0, 0, 0);
      }
    }
  }
#pragma unroll
  for (int m = 0; m < 2; ++m)
#pragma unroll
    for (int n = 0; n < 4; ++n)
#pragma unroll
      for (int j = 0; j < 4; ++j) {
        const int t = q0 + m * 16 + lb * 4 + j;
        const int c = h * 64 + n * 16 + la;
        Y[((size_t)b * 2048 + t) * 1024 + c] = f2bf(o[m][n][j] / lrow[m][j]);
      }
}

extern "C" void kernel_launch(void* const* d_in, const int* in_sizes, int n_in, void* d_out,
                              int out_size, void* d_ws, size_t ws_size, hipStream_t stream) {
  (void)in_sizes; (void)n_in; (void)out_size; (void)ws_size;
  const float* x = (const float*)d_in[0];
  const float* w_qkv = (const float*)d_in[1];
  const float* w_proj = (const float*)d_in[2];
  char* ws = (char*)d_ws;
  // workspace layout (bytes), total 64 MiB
  u16* xb     = (u16*)(ws);             // 4096*1024 bf16  (8 MiB)  -- reused as y later
  u16* wqkvT  = (u16*)(ws + 8388608);   // 3072*1024       (6 MiB)
  u16* wprojT = (u16*)(ws + 14680064);  // 1024*1024       (2 MiB)
  u16* qkv    = (u16*)(ws + 16777216);  // 4096*3072       (24 MiB)
  u16* q      = (u16*)(ws + 41943040);  // 32*2048*64      (8 MiB)
  u16* k      = (u16*)(ws + 50331648);  // 32*2048*64      (8 MiB)
  u16* vt     = (u16*)(ws + 58720256);  // 32*64*2048      (8 MiB)
  u16* y      = xb;                     // alias: xb dead after GEMM1

  cvt_kernel<<<dim3(4096), dim3(256), 0, stream>>>(x, xb);
  transpose_w<<<dim3(48, 16), dim3(256), 0, stream>>>(w_qkv, wqkvT, 1024, 3072);
  transpose_w<<<dim3(16, 16), dim3(256), 0, stream>>>(w_proj, wprojT, 1024, 1024);
  gemm_bt<0><<<dim3(32, 24), dim3(256), 0, stream>>>(xb, wqkvT, (void*)qkv, 4096, 3072, 1024);
  rope_kernel<<<dim3(32, 32), dim3(256), 0, stream>>>(qkv, q, k, vt);
  attn_kernel<<<dim3(16, 32), dim3(256), 0, stream>>>(q, k, vt, y);
  gemm_bt<1><<<dim3(32, 8), dim3(256), 0, stream>>>(y, wprojT, d_out, 4096, 1024, 1024);
}

// Round 2
// 206.266 us; speedup vs baseline: 1.3916x; 1.3916x over previous
//
#include <hip/hip_runtime.h>
#include <hip/hip_bf16.h>

typedef unsigned short u16;
typedef unsigned int u32;
typedef __attribute__((ext_vector_type(8))) __bf16 bf16x8;
typedef __attribute__((ext_vector_type(4))) float f32x4;
typedef __attribute__((ext_vector_type(4))) u16 u16x4;

__device__ __forceinline__ u16 f2bf(float f) {
  u32 u = __builtin_bit_cast(u32, f);
  u32 r = (u + 0x7fffu + ((u >> 16) & 1u)) >> 16;
  return (u16)r;
}
__device__ __forceinline__ float bf2f(u16 h) {
  return __builtin_bit_cast(float, (u32)h << 16);
}

__device__ __forceinline__ void gload_lds16(const void* g, void* l) {
  __builtin_amdgcn_global_load_lds((const __attribute__((address_space(1))) void*)g,
                                   (__attribute__((address_space(3))) void*)l, 16, 0, 0);
}

// ---------------- fp32 -> bf16 convert (x) ----------------
__global__ __launch_bounds__(256) void cvt_kernel(const float* __restrict__ in, u16* __restrict__ out) {
  const int i = (blockIdx.x * 256 + threadIdx.x) * 4;
  const float4 v = *(const float4*)(in + i);
  u16x4 r = {f2bf(v.x), f2bf(v.y), f2bf(v.z), f2bf(v.w)};
  *(u16x4*)(out + i) = r;
}

// ---------------- transpose + convert weights: w[K][N] f32 -> wt[N][K] bf16 ----------------
__global__ __launch_bounds__(256) void transpose_w(const float* __restrict__ w, u16* __restrict__ wt,
                                                   int K, int N) {
  __shared__ u16 tile[64][65];
  const int n0 = blockIdx.x * 64, k0 = blockIdx.y * 64;
  const int tid = threadIdx.x;
#pragma unroll
  for (int it = 0; it < 16; ++it) {
    const int idx = it * 256 + tid;
    const int r = idx >> 6, c = idx & 63;
    tile[r][c] = f2bf(w[(size_t)(k0 + r) * N + n0 + c]);
  }
  __syncthreads();
#pragma unroll
  for (int it = 0; it < 16; ++it) {
    const int idx = it * 256 + tid;
    const int r2 = idx >> 6, c2 = idx & 63;
    wt[(size_t)(n0 + r2) * K + k0 + c2] = tile[c2][r2];
  }
}

// ---------------- bf16 GEMM: C[M][N] = A[M][K] * Bt[N][K]^T  (m97 structure) ----------------
template <int OUT_F32>
__global__ __launch_bounds__(256) void gemm_bt(const u16* __restrict__ A, const u16* __restrict__ Bt,
                                               void* __restrict__ Cout, int M, int N, int K) {
  __shared__ u16 As[128 * 32];
  __shared__ u16 Bs[128 * 32];
  const int tid = threadIdx.x;
  const int wave = tid >> 6;
  const int lane = tid & 63;
  const int la = lane & 15, lb = lane >> 4;
  const int m0 = blockIdx.x * 128, n0 = blockIdx.y * 128;
  const int wr = (wave >> 1) * 64, wc = (wave & 1) * 64;
  const int srow = lane >> 2;       // 0..15
  const int scol = (lane & 3) * 8;  // 0,8,16,24
  const int c0 = wave * 2;
  f32x4 acc[4][4] = {};
  for (int k0 = 0; k0 < K; k0 += 32) {
#pragma unroll
    for (int c2 = 0; c2 < 2; ++c2) {
      const int c = c0 + c2;
      const int row = c * 16 + srow;
      gload_lds16(A + (size_t)(m0 + row) * K + k0 + scol, As + c * 512);
      gload_lds16(Bt + (size_t)(n0 + row) * K + k0 + scol, Bs + c * 512);
    }
    __syncthreads();
    bf16x8 af[4], bfr[4];
#pragma unroll
    for (int m = 0; m < 4; ++m) af[m] = *(const bf16x8*)&As[(wr + m * 16 + la) * 32 + lb * 8];
#pragma unroll
    for (int n = 0; n < 4; ++n) bfr[n] = *(const bf16x8*)&Bs[(wc + n * 16 + la) * 32 + lb * 8];
#pragma unroll
    for (int m = 0; m < 4; ++m)
#pragma unroll
      for (int n = 0; n < 4; ++n)
        acc[m][n] = __builtin_amdgcn_mfma_f32_16x16x32_bf16(af[m], bfr[n], acc[m][n], 0, 0, 0);
    __syncthreads();
  }
#pragma unroll
  for (int m = 0; m < 4; ++m)
#pragma unroll
    for (int n = 0; n < 4; ++n)
#pragma unroll
      for (int j = 0; j < 4; ++j) {
        const int row = m0 + wr + m * 16 + lb * 4 + j;
        const int col = n0 + wc + n * 16 + la;
        if (OUT_F32)
          ((float*)Cout)[(size_t)row * N + col] = acc[m][n][j];
        else
          ((u16*)Cout)[(size_t)row * N + col] = f2bf(acc[m][n][j]);
      }
}

// ---------------- RoPE + head reshape + V transpose ----------------
// qkv[b][t][3072] bf16 -> q[bh][t][64] (roped, *0.125*log2e), k[bh][t][64] (roped), vt[bh][64][2048]
__global__ __launch_bounds__(256) void rope_kernel(const u16* __restrict__ QKV, u16* __restrict__ Q,
                                                   u16* __restrict__ K, u16* __restrict__ Vt) {
  const int tt = blockIdx.x * 64;
  const int bh = blockIdx.y;
  const int b = bh >> 4, h = bh & 15;
  const int tid = threadIdx.x;
  __shared__ u16 vtile[64][65];
  const float NEG = -0.41524101186f;  // -log2(10000)/32
  const float QSC = 0.18033688011f;   // 0.125 * log2(e)
#pragma unroll
  for (int it = 0; it < 8; ++it) {
    const int idx = it * 256 + tid;
    const int tl = idx >> 5, i = idx & 31;
    const int t = tt + tl;
    const int d0 = 2 * i;
    const int j0 = d0 & 31, j1 = (d0 + 1) & 31;
    const float a0 = (float)t * exp2f(NEG * (float)j0);
    const float a1 = (float)t * exp2f(NEG * (float)j1);
    float s0, c0v, s1, c1v;
    sincosf(a0, &s0, &c0v);
    sincosf(a1, &s1, &c1v);
    const size_t base = ((size_t)(b * 2048 + t)) * 3072 + h * 64 + d0;
    const size_t ob = ((size_t)bh * 2048 + t) * 64 + d0;
    {
      const float x0 = bf2f(QKV[base]), x1 = bf2f(QKV[base + 1]);
      Q[ob] = f2bf((x0 * c0v - x1 * s0) * QSC);
      Q[ob + 1] = f2bf((x1 * c1v + x0 * s1) * QSC);
    }
    {
      const float x0 = bf2f(QKV[base + 1024]), x1 = bf2f(QKV[base + 1025]);
      K[ob] = f2bf(x0 * c0v - x1 * s0);
      K[ob + 1] = f2bf(x1 * c1v + x0 * s1);
    }
  }
  // V transpose through LDS
#pragma unroll
  for (int it = 0; it < 8; ++it) {
    const int idx = it * 256 + tid;
    const int tl = idx >> 5, d0 = (idx & 31) * 2;
    const size_t base = ((size_t)(b * 2048 + tt + tl)) * 3072 + 2048 + h * 64 + d0;
    vtile[tl][d0] = QKV[base];
    vtile[tl][d0 + 1] = QKV[base + 1];
  }
  __syncthreads();
#pragma unroll
  for (int it = 0; it < 8; ++it) {
    const int idx = it * 256 + tid;
    const int dl = idx >> 5, tp = (idx & 31) * 2;
    const u32 val = (u32)vtile[tp][dl] | ((u32)vtile[tp + 1][dl] << 16);
    *(u32*)(Vt + ((size_t)bh * 64 + dl) * 2048 + tt + tp) = val;
  }
}

// ---------------- flash attention (causal), mirrored 16-row strip pairs ----------------
// Each wave owns strips q0 = p*16 and (127-p)*16 -> uniform ~33 strip-tiles per wave.
// Deferred max (vote on lane-local maxima), deferred row-sum (per-lane partials,
// one cross-lane reduce at the end), exp2-based softmax, padded P LDS (stride 72).
__global__ __launch_bounds__(256) void attn_kernel(const u16* __restrict__ Q, const u16* __restrict__ K,
                                                   const u16* __restrict__ Vt, u16* __restrict__ Y) {
  const int bh = blockIdx.y;
  const int b = bh >> 4, h = bh & 15;
  const int wave = threadIdx.x >> 6, lane = threadIdx.x & 63;
  const int la = lane & 15, lb = lane >> 4;
  const int pairIdx = blockIdx.x * 4 + wave;  // 0..63
  const int q0s[2] = {pairIdx * 16, (127 - pairIdx) * 16};
  __shared__ __align__(16) u16 Plds[4][2][16 * 72];
  const size_t plane = (size_t)bh * (2048 * 64);

  bf16x8 qf[2][2];
#pragma unroll
  for (int st = 0; st < 2; ++st)
#pragma unroll
    for (int s = 0; s < 2; ++s)
      qf[st][s] = *(const bf16x8*)(Q + plane + (size_t)(q0s[st] + la) * 64 + s * 32 + lb * 8);

  f32x4 o[2][4] = {};
  float mrow[2][4], plr[2][4];
#pragma unroll
  for (int st = 0; st < 2; ++st)
#pragma unroll
    for (int j = 0; j < 4; ++j) {
      mrow[st][j] = -1.0e30f;
      plr[st][j] = 0.f;
    }
  const int ktEnd0 = (q0s[0] + 79) >> 6;
  const int ktEnd1 = (q0s[1] + 79) >> 6;

  bf16x8 kf[2][4];
#pragma unroll
  for (int s = 0; s < 2; ++s)
#pragma unroll
    for (int n = 0; n < 4; ++n)
      kf[s][n] = *(const bf16x8*)(K + plane + (size_t)(n * 16 + la) * 64 + s * 32 + lb * 8);

  for (int kt = 0; kt < ktEnd1; ++kt) {
    // V fragments for this tile (shared by both strips)
    bf16x8 vf[2][4];
#pragma unroll
    for (int s = 0; s < 2; ++s)
#pragma unroll
      for (int n = 0; n < 4; ++n)
        vf[s][n] = *(const bf16x8*)(Vt + plane + (size_t)(n * 16 + la) * 2048 + kt * 64 + s * 32 + lb * 8);

    // ---- QK^T + online softmax per strip ----
#pragma unroll
    for (int st = 0; st < 2; ++st) {
      if (st == 0 && kt >= ktEnd0) continue;
      const int q0 = q0s[st];
      f32x4 sa[4] = {};
#pragma unroll
      for (int s = 0; s < 2; ++s)
#pragma unroll
        for (int n = 0; n < 4; ++n)
          sa[n] = __builtin_amdgcn_mfma_f32_16x16x32_bf16(qf[st][s], kf[s][n], sa[n], 0, 0, 0);
      if (kt * 64 + 63 > q0) {
#pragma unroll
        for (int n = 0; n < 4; ++n)
#pragma unroll
          for (int j = 0; j < 4; ++j) {
            const int row = q0 + lb * 4 + j;
            const int col = kt * 64 + n * 16 + la;
            if (col > row) sa[n][j] = -1.0e30f;
          }
      }
      float lmax[4];
      int need = 0;
#pragma unroll
      for (int j = 0; j < 4; ++j) {
        lmax[j] = fmaxf(fmaxf(sa[0][j], sa[1][j]), fmaxf(sa[2][j], sa[3][j]));
        need |= (lmax[j] > mrow[st][j] + 8.0f);
      }
      if (__any(need)) {
#pragma unroll
        for (int j = 0; j < 4; ++j) {
          float v = lmax[j];
#pragma unroll
          for (int off = 1; off < 16; off <<= 1) v = fmaxf(v, __shfl_xor(v, off));
          const float mn = fmaxf(mrow[st][j], v);
          const float al = __builtin_amdgcn_exp2f(mrow[st][j] - mn);
          plr[st][j] *= al;
#pragma unroll
          for (int n = 0; n < 4; ++n) o[st][n][j] *= al;
          mrow[st][j] = mn;
        }
      }
      u16* pw = &Plds[wave][st][0];
#pragma unroll
      for (int j = 0; j < 4; ++j) {
        float ps = 0.f;
#pragma unroll
        for (int n = 0; n < 4; ++n) {
          const float p = __builtin_amdgcn_exp2f(sa[n][j] - mrow[st][j]);
          ps += p;
          pw[(lb * 4 + j) * 72 + n * 16 + la] = f2bf(p);
        }
        plr[st][j] += ps;
      }
    }

    // prefetch next K tile (current kf fully consumed above)
    if (kt + 1 < ktEnd1) {
#pragma unroll
      for (int s = 0; s < 2; ++s)
#pragma unroll
        for (int n = 0; n < 4; ++n)
          kf[s][n] = *(const bf16x8*)(K + plane + (size_t)((kt + 1) * 64 + n * 16 + la) * 64 + s * 32 + lb * 8);
    }

    // ---- PV per strip ----
#pragma unroll
    for (int st = 0; st < 2; ++st) {
      if (st == 0 && kt >= ktEnd0) continue;
      const u16* pw = &Plds[wave][st][0];
      bf16x8 pf[2];
#pragma unroll
      for (int s = 0; s < 2; ++s) pf[s] = *(const bf16x8*)&pw[la * 72 + s * 32 + lb * 8];
#pragma unroll
      for (int n = 0; n < 4; ++n)
#pragma unroll
        for (int s = 0; s < 2; ++s)
          o[st][n] = __builtin_amdgcn_mfma_f32_16x16x32_bf16(pf[s], vf[s][n], o[st][n], 0, 0, 0);
    }
  }

  // epilogue: one cross-lane row-sum reduce, then scaled write
#pragma unroll
  for (int st = 0; st < 2; ++st) {
    float rinv[4];
#pragma unroll
    for (int j = 0; j < 4; ++j) {
      float ls = plr[st][j];
#pragma unroll
      for (int off = 1; off < 16; off <<= 1) ls += __shfl_xor(ls, off);
      rinv[j] = __builtin_amdgcn_rcpf(ls);
    }
#pragma unroll
    for (int n = 0; n < 4; ++n)
#pragma unroll
      for (int j = 0; j < 4; ++j) {
        const int t = q0s[st] + lb * 4 + j;
        const int c = h * 64 + n * 16 + la;
        Y[((size_t)b * 2048 + t) * 1024 + c] = f2bf(o[st][n][j] * rinv[j]);
      }
  }
}

extern "C" void kernel_launch(void* const* d_in, const int* in_sizes, int n_in, void* d_out,
                              int out_size, void* d_ws, size_t ws_size, hipStream_t stream) {
  (void)in_sizes; (void)n_in; (void)out_size; (void)ws_size;
  const float* x = (const float*)d_in[0];
  const float* w_qkv = (const float*)d_in[1];
  const float* w_proj = (const float*)d_in[2];
  char* ws = (char*)d_ws;
  // workspace layout (bytes), total 64 MiB
  u16* xb     = (u16*)(ws);             // 4096*1024 bf16  (8 MiB)  -- reused as y later
  u16* wqkvT  = (u16*)(ws + 8388608);   // 3072*1024       (6 MiB)
  u16* wprojT = (u16*)(ws + 14680064);  // 1024*1024       (2 MiB)
  u16* qkv    = (u16*)(ws + 16777216);  // 4096*3072       (24 MiB)
  u16* q      = (u16*)(ws + 41943040);  // 32*2048*64      (8 MiB)
  u16* k      = (u16*)(ws + 50331648);  // 32*2048*64      (8 MiB)
  u16* vt     = (u16*)(ws + 58720256);  // 32*64*2048      (8 MiB)
  u16* y      = xb;                     // alias: xb dead after GEMM1

  cvt_kernel<<<dim3(4096), dim3(256), 0, stream>>>(x, xb);
  transpose_w<<<dim3(48, 16), dim3(256), 0, stream>>>(w_qkv, wqkvT, 1024, 3072);
  transpose_w<<<dim3(16, 16), dim3(256), 0, stream>>>(w_proj, wprojT, 1024, 1024);
  gemm_bt<0><<<dim3(32, 24), dim3(256), 0, stream>>>(xb, wqkvT, (void*)qkv, 4096, 3072, 1024);
  rope_kernel<<<dim3(32, 32), dim3(256), 0, stream>>>(qkv, q, k, vt);
  attn_kernel<<<dim3(16, 32), dim3(256), 0, stream>>>(q, k, vt, y);
  gemm_bt<1><<<dim3(32, 8), dim3(256), 0, stream>>>(y, wprojT, d_out, 4096, 1024, 1024);
}

// Round 3
// 205.415 us; speedup vs baseline: 1.3974x; 1.0041x over previous
//
#include <hip/hip_runtime.h>
#include <hip/hip_bf16.h>

typedef unsigned short u16;
typedef unsigned int u32;
typedef __attribute__((ext_vector_type(8))) __bf16 bf16x8;
typedef __attribute__((ext_vector_type(4))) float f32x4;
typedef __attribute__((ext_vector_type(4))) u16 u16x4;

__device__ __forceinline__ u16 f2bf(float f) {
  u32 u = __builtin_bit_cast(u32, f);
  u32 r = (u + 0x7fffu + ((u >> 16) & 1u)) >> 16;
  return (u16)r;
}
__device__ __forceinline__ float bf2f(u16 h) {
  return __builtin_bit_cast(float, (u32)h << 16);
}

__device__ __forceinline__ void gload_lds16(const void* g, void* l) {
  __builtin_amdgcn_global_load_lds((const __attribute__((address_space(1))) void*)g,
                                   (__attribute__((address_space(3))) void*)l, 16, 0, 0);
}

// ---------------- fp32 -> bf16 convert (x) ----------------
__global__ __launch_bounds__(256) void cvt_kernel(const float* __restrict__ in, u16* __restrict__ out) {
  const int i = (blockIdx.x * 256 + threadIdx.x) * 4;
  const float4 v = *(const float4*)(in + i);
  u16x4 r = {f2bf(v.x), f2bf(v.y), f2bf(v.z), f2bf(v.w)};
  *(u16x4*)(out + i) = r;
}

// ---------------- transpose + convert weights: w[K][N] f32 -> wt[N][K] bf16 ----------------
__global__ __launch_bounds__(256) void transpose_w(const float* __restrict__ w, u16* __restrict__ wt,
                                                   int K, int N) {
  __shared__ u16 tile[64][65];
  const int n0 = blockIdx.x * 64, k0 = blockIdx.y * 64;
  const int tid = threadIdx.x;
#pragma unroll
  for (int it = 0; it < 16; ++it) {
    const int idx = it * 256 + tid;
    const int r = idx >> 6, c = idx & 63;
    tile[r][c] = f2bf(w[(size_t)(k0 + r) * N + n0 + c]);
  }
  __syncthreads();
#pragma unroll
  for (int it = 0; it < 16; ++it) {
    const int idx = it * 256 + tid;
    const int r2 = idx >> 6, c2 = idx & 63;
    wt[(size_t)(n0 + r2) * K + k0 + c2] = tile[c2][r2];
  }
}

// ---------------- bf16 GEMM: C[M][N] = A[M][K] * Bt[N][K]^T  (m97 structure) ----------------
template <int OUT_F32>
__global__ __launch_bounds__(256) void gemm_bt(const u16* __restrict__ A, const u16* __restrict__ Bt,
                                               void* __restrict__ Cout, int M, int N, int K) {
  __shared__ u16 As[128 * 32];
  __shared__ u16 Bs[128 * 32];
  const int tid = threadIdx.x;
  const int wave = tid >> 6;
  const int lane = tid & 63;
  const int la = lane & 15, lb = lane >> 4;
  const int m0 = blockIdx.x * 128, n0 = blockIdx.y * 128;
  const int wr = (wave >> 1) * 64, wc = (wave & 1) * 64;
  const int srow = lane >> 2;       // 0..15
  const int scol = (lane & 3) * 8;  // 0,8,16,24
  const int c0 = wave * 2;
  f32x4 acc[4][4] = {};
  for (int k0 = 0; k0 < K; k0 += 32) {
#pragma unroll
    for (int c2 = 0; c2 < 2; ++c2) {
      const int c = c0 + c2;
      const int row = c * 16 + srow;
      gload_lds16(A + (size_t)(m0 + row) * K + k0 + scol, As + c * 512);
      gload_lds16(Bt + (size_t)(n0 + row) * K + k0 + scol, Bs + c * 512);
    }
    __syncthreads();
    bf16x8 af[4], bfr[4];
#pragma unroll
    for (int m = 0; m < 4; ++m) af[m] = *(const bf16x8*)&As[(wr + m * 16 + la) * 32 + lb * 8];
#pragma unroll
    for (int n = 0; n < 4; ++n) bfr[n] = *(const bf16x8*)&Bs[(wc + n * 16 + la) * 32 + lb * 8];
#pragma unroll
    for (int m = 0; m < 4; ++m)
#pragma unroll
      for (int n = 0; n < 4; ++n)
        acc[m][n] = __builtin_amdgcn_mfma_f32_16x16x32_bf16(af[m], bfr[n], acc[m][n], 0, 0, 0);
    __syncthreads();
  }
#pragma unroll
  for (int m = 0; m < 4; ++m)
#pragma unroll
    for (int n = 0; n < 4; ++n)
#pragma unroll
      for (int j = 0; j < 4; ++j) {
        const int row = m0 + wr + m * 16 + lb * 4 + j;
        const int col = n0 + wc + n * 16 + la;
        if (OUT_F32)
          ((float*)Cout)[(size_t)row * N + col] = acc[m][n][j];
        else
          ((u16*)Cout)[(size_t)row * N + col] = f2bf(acc[m][n][j]);
      }
}

// ---------------- RoPE + head reshape + V transpose ----------------
// qkv[b][t][3072] bf16 -> q[bh][t][64] (roped, *0.125*log2e), k[bh][t][64] (roped), vt[bh][64][2048]
__global__ __launch_bounds__(256) void rope_kernel(const u16* __restrict__ QKV, u16* __restrict__ Q,
                                                   u16* __restrict__ K, u16* __restrict__ Vt) {
  const int tt = blockIdx.x * 64;
  const int bh = blockIdx.y;
  const int b = bh >> 4, h = bh & 15;
  const int tid = threadIdx.x;
  __shared__ u16 vtile[64][65];
  const float NEG = -0.41524101186f;  // -log2(10000)/32
  const float QSC = 0.18033688011f;   // 0.125 * log2(e)
#pragma unroll
  for (int it = 0; it < 8; ++it) {
    const int idx = it * 256 + tid;
    const int tl = idx >> 5, i = idx & 31;
    const int t = tt + tl;
    const int d0 = 2 * i;
    const int j0 = d0 & 31, j1 = (d0 + 1) & 31;
    const float a0 = (float)t * exp2f(NEG * (float)j0);
    const float a1 = (float)t * exp2f(NEG * (float)j1);
    float s0, c0v, s1, c1v;
    sincosf(a0, &s0, &c0v);
    sincosf(a1, &s1, &c1v);
    const size_t base = ((size_t)(b * 2048 + t)) * 3072 + h * 64 + d0;
    const size_t ob = ((size_t)bh * 2048 + t) * 64 + d0;
    {
      const float x0 = bf2f(QKV[base]), x1 = bf2f(QKV[base + 1]);
      Q[ob] = f2bf((x0 * c0v - x1 * s0) * QSC);
      Q[ob + 1] = f2bf((x1 * c1v + x0 * s1) * QSC);
    }
    {
      const float x0 = bf2f(QKV[base + 1024]), x1 = bf2f(QKV[base + 1025]);
      K[ob] = f2bf(x0 * c0v - x1 * s0);
      K[ob + 1] = f2bf(x1 * c1v + x0 * s1);
    }
  }
  // V transpose through LDS
#pragma unroll
  for (int it = 0; it < 8; ++it) {
    const int idx = it * 256 + tid;
    const int tl = idx >> 5, d0 = (idx & 31) * 2;
    const size_t base = ((size_t)(b * 2048 + tt + tl)) * 3072 + 2048 + h * 64 + d0;
    vtile[tl][d0] = QKV[base];
    vtile[tl][d0 + 1] = QKV[base + 1];
  }
  __syncthreads();
#pragma unroll
  for (int it = 0; it < 8; ++it) {
    const int idx = it * 256 + tid;
    const int dl = idx >> 5, tp = (idx & 31) * 2;
    const u32 val = (u32)vtile[tp][dl] | ((u32)vtile[tp + 1][dl] << 16);
    *(u32*)(Vt + ((size_t)bh * 64 + dl) * 2048 + tt + tp) = val;
  }
}

// ---------------- flash attention (causal), mirrored strip pairs + kv-parity split ----------------
// 2048 blocks x 2 waves. Block owns strips q0 = p*16 and (127-p)*16 (uniform ~34 strip-tiles).
// Wave w handles kv-tiles kt === w (mod 2) with private (m,l,o); waves merged via LDS at the end.
__global__ __launch_bounds__(128) void attn_kernel(const u16* __restrict__ Q, const u16* __restrict__ K,
                                                   const u16* __restrict__ Vt, u16* __restrict__ Y) {
  const int bh = blockIdx.y;
  const int b = bh >> 4, h = bh & 15;
  const int wave = threadIdx.x >> 6, lane = threadIdx.x & 63;
  const int la = lane & 15, lb = lane >> 4;
  const int pairIdx = blockIdx.x;  // 0..63
  const int q0s[2] = {pairIdx * 16, (127 - pairIdx) * 16};
  __shared__ __align__(16) char smem[12288];  // P staging (9216B) overlaid by combine buf (12288B)
  u16* PldsW = (u16*)smem + wave * 2304;      // 2 strips x 16*72 u16 per wave
  const size_t plane = (size_t)bh * (2048 * 64);

  bf16x8 qf[2][2];
#pragma unroll
  for (int st = 0; st < 2; ++st)
#pragma unroll
    for (int s = 0; s < 2; ++s)
      qf[st][s] = *(const bf16x8*)(Q + plane + (size_t)(q0s[st] + la) * 64 + s * 32 + lb * 8);

  f32x4 o[2][4] = {};
  float mrow[2][4], plr[2][4];
#pragma unroll
  for (int st = 0; st < 2; ++st)
#pragma unroll
    for (int j = 0; j < 4; ++j) {
      mrow[st][j] = -1.0e30f;
      plr[st][j] = 0.f;
    }
  const int ktEnd0 = (q0s[0] + 79) >> 6;
  const int ktEnd1 = (q0s[1] + 79) >> 6;  // >= 17 always

  bf16x8 kf[2][4];
#pragma unroll
  for (int s = 0; s < 2; ++s)
#pragma unroll
    for (int n = 0; n < 4; ++n)
      kf[s][n] = *(const bf16x8*)(K + plane + (size_t)(wave * 64 + n * 16 + la) * 64 + s * 32 + lb * 8);

  for (int kt = wave; kt < ktEnd1; kt += 2) {
    // V fragments for this tile (shared by both strips)
    bf16x8 vf[2][4];
#pragma unroll
    for (int s = 0; s < 2; ++s)
#pragma unroll
      for (int n = 0; n < 4; ++n)
        vf[s][n] = *(const bf16x8*)(Vt + plane + (size_t)(n * 16 + la) * 2048 + kt * 64 + s * 32 + lb * 8);

    // ---- QK^T + online softmax per strip ----
#pragma unroll
    for (int st = 0; st < 2; ++st) {
      if (st == 0 && kt >= ktEnd0) continue;
      const int q0 = q0s[st];
      f32x4 sa[4] = {};
#pragma unroll
      for (int s = 0; s < 2; ++s)
#pragma unroll
        for (int n = 0; n < 4; ++n)
          sa[n] = __builtin_amdgcn_mfma_f32_16x16x32_bf16(qf[st][s], kf[s][n], sa[n], 0, 0, 0);
      if (kt * 64 + 63 > q0) {
#pragma unroll
        for (int n = 0; n < 4; ++n)
#pragma unroll
          for (int j = 0; j < 4; ++j) {
            const int row = q0 + lb * 4 + j;
            const int col = kt * 64 + n * 16 + la;
            if (col > row) sa[n][j] = -1.0e30f;
          }
      }
      float lmax[4];
      int need = 0;
#pragma unroll
      for (int j = 0; j < 4; ++j) {
        lmax[j] = fmaxf(fmaxf(sa[0][j], sa[1][j]), fmaxf(sa[2][j], sa[3][j]));
        need |= (lmax[j] > mrow[st][j] + 8.0f);
      }
      if (__any(need)) {
#pragma unroll
        for (int j = 0; j < 4; ++j) {
          float v = lmax[j];
#pragma unroll
          for (int off = 1; off < 16; off <<= 1) v = fmaxf(v, __shfl_xor(v, off));
          const float mn = fmaxf(mrow[st][j], v);
          const float al = __builtin_amdgcn_exp2f(mrow[st][j] - mn);
          plr[st][j] *= al;
#pragma unroll
          for (int n = 0; n < 4; ++n) o[st][n][j] *= al;
          mrow[st][j] = mn;
        }
      }
      u16* pw = PldsW + st * 1152;
#pragma unroll
      for (int j = 0; j < 4; ++j) {
        float ps = 0.f;
#pragma unroll
        for (int n = 0; n < 4; ++n) {
          const float p = __builtin_amdgcn_exp2f(sa[n][j] - mrow[st][j]);
          ps += p;
          pw[(lb * 4 + j) * 72 + n * 16 + la] = f2bf(p);
        }
        plr[st][j] += ps;
      }
    }

    // prefetch this wave's next K tile (current kf fully consumed above)
    if (kt + 2 < ktEnd1) {
#pragma unroll
      for (int s = 0; s < 2; ++s)
#pragma unroll
        for (int n = 0; n < 4; ++n)
          kf[s][n] = *(const bf16x8*)(K + plane + (size_t)((kt + 2) * 64 + n * 16 + la) * 64 + s * 32 + lb * 8);
    }

    // ---- PV per strip ----
#pragma unroll
    for (int st = 0; st < 2; ++st) {
      if (st == 0 && kt >= ktEnd0) continue;
      const u16* pw = PldsW + st * 1152;
      bf16x8 pf[2];
#pragma unroll
      for (int s = 0; s < 2; ++s) pf[s] = *(const bf16x8*)&pw[la * 72 + s * 32 + lb * 8];
#pragma unroll
      for (int n = 0; n < 4; ++n)
#pragma unroll
        for (int s = 0; s < 2; ++s)
          o[st][n] = __builtin_amdgcn_mfma_f32_16x16x32_bf16(pf[s], vf[s][n], o[st][n], 0, 0, 0);
    }
  }

  // ---- cross-wave merge: wave1 publishes (o,m,l), wave0 combines + writes ----
  __syncthreads();  // all PV done; P staging LDS now dead
  float* cmb = (float*)smem;
  if (wave == 1) {
#pragma unroll
    for (int st = 0; st < 2; ++st) {
#pragma unroll
      for (int n = 0; n < 4; ++n)
#pragma unroll
        for (int j = 0; j < 4; ++j)
          cmb[(((st * 4 + n) * 4 + j)) * 64 + lane] = o[st][n][j];
#pragma unroll
      for (int j = 0; j < 4; ++j) {
        cmb[(32 + st * 4 + j) * 64 + lane] = mrow[st][j];
        cmb[(40 + st * 4 + j) * 64 + lane] = plr[st][j];
      }
    }
  }
  __syncthreads();
  if (wave == 0) {
#pragma unroll
    for (int st = 0; st < 2; ++st) {
      float aA[4], aB[4], rinv[4];
#pragma unroll
      for (int j = 0; j < 4; ++j) {
        const float mB = cmb[(32 + st * 4 + j) * 64 + lane];
        const float lB = cmb[(40 + st * 4 + j) * 64 + lane];
        const float mA = mrow[st][j];
        const float mx = fmaxf(mA, mB);
        aA[j] = __builtin_amdgcn_exp2f(mA - mx);
        aB[j] = __builtin_amdgcn_exp2f(mB - mx);
        float l = plr[st][j] * aA[j] + lB * aB[j];
#pragma unroll
        for (int off = 1; off < 16; off <<= 1) l += __shfl_xor(l, off);
        rinv[j] = __builtin_amdgcn_rcpf(l);
      }
#pragma unroll
      for (int n = 0; n < 4; ++n)
#pragma unroll
        for (int j = 0; j < 4; ++j) {
          const float ov = o[st][n][j] * aA[j] + cmb[((st * 4 + n) * 4 + j) * 64 + lane] * aB[j];
          const int t = q0s[st] + lb * 4 + j;
          const int c = h * 64 + n * 16 + la;
          Y[((size_t)b * 2048 + t) * 1024 + c] = f2bf(ov * rinv[j]);
        }
    }
  }
}

extern "C" void kernel_launch(void* const* d_in, const int* in_sizes, int n_in, void* d_out,
                              int out_size, void* d_ws, size_t ws_size, hipStream_t stream) {
  (void)in_sizes; (void)n_in; (void)out_size; (void)ws_size;
  const float* x = (const float*)d_in[0];
  const float* w_qkv = (const float*)d_in[1];
  const float* w_proj = (const float*)d_in[2];
  char* ws = (char*)d_ws;
  // workspace layout (bytes), total 64 MiB
  u16* xb     = (u16*)(ws);             // 4096*1024 bf16  (8 MiB)  -- reused as y later
  u16* wqkvT  = (u16*)(ws + 8388608);   // 3072*1024       (6 MiB)
  u16* wprojT = (u16*)(ws + 14680064);  // 1024*1024       (2 MiB)
  u16* qkv    = (u16*)(ws + 16777216);  // 4096*3072       (24 MiB)
  u16* q      = (u16*)(ws + 41943040);  // 32*2048*64      (8 MiB)
  u16* k      = (u16*)(ws + 50331648);  // 32*2048*64      (8 MiB)
  u16* vt     = (u16*)(ws + 58720256);  // 32*64*2048      (8 MiB)
  u16* y      = xb;                     // alias: xb dead after GEMM1

  cvt_kernel<<<dim3(4096), dim3(256), 0, stream>>>(x, xb);
  transpose_w<<<dim3(48, 16), dim3(256), 0, stream>>>(w_qkv, wqkvT, 1024, 3072);
  transpose_w<<<dim3(16, 16), dim3(256), 0, stream>>>(w_proj, wprojT, 1024, 1024);
  gemm_bt<0><<<dim3(32, 24), dim3(256), 0, stream>>>(xb, wqkvT, (void*)qkv, 4096, 3072, 1024);
  rope_kernel<<<dim3(32, 32), dim3(256), 0, stream>>>(qkv, q, k, vt);
  attn_kernel<<<dim3(64, 32), dim3(128), 0, stream>>>(q, k, vt, y);
  gemm_bt<1><<<dim3(32, 8), dim3(256), 0, stream>>>(y, wprojT, d_out, 4096, 1024, 1024);
}

// Round 4
// 135.441 us; speedup vs baseline: 2.1193x; 1.5166x over previous
//
#include <hip/hip_runtime.h>
#include <hip/hip_bf16.h>

typedef unsigned short u16;
typedef unsigned int u32;
typedef __attribute__((ext_vector_type(8))) __bf16 bf16x8;
typedef __attribute__((ext_vector_type(4))) float f32x4;
typedef __attribute__((ext_vector_type(4))) u16 u16x4;

__device__ __forceinline__ u16 f2bf(float f) {
  return __builtin_bit_cast(u16, (__bf16)f);  // native RNE cvt (m240: compiler handles)
}
__device__ __forceinline__ float bf2f(u16 h) {
  return __builtin_bit_cast(float, (u32)h << 16);
}

__device__ __forceinline__ void gload_lds16(const void* g, void* l) {
  __builtin_amdgcn_global_load_lds((const __attribute__((address_space(1))) void*)g,
                                   (__attribute__((address_space(3))) void*)l, 16, 0, 0);
}

// ---------------- fp32 -> bf16 convert (x) ----------------
__global__ __launch_bounds__(256) void cvt_kernel(const float* __restrict__ in, u16* __restrict__ out) {
  const int i = (blockIdx.x * 256 + threadIdx.x) * 4;
  const float4 v = *(const float4*)(in + i);
  u16x4 r = {f2bf(v.x), f2bf(v.y), f2bf(v.z), f2bf(v.w)};
  *(u16x4*)(out + i) = r;
}

// ---------------- transpose + convert weights: w[K][N] f32 -> wt[N][K] bf16 ----------------
__global__ __launch_bounds__(256) void transpose_w(const float* __restrict__ w, u16* __restrict__ wt,
                                                   int K, int N) {
  __shared__ u16 tile[64][65];
  const int n0 = blockIdx.x * 64, k0 = blockIdx.y * 64;
  const int tid = threadIdx.x;
#pragma unroll
  for (int it = 0; it < 16; ++it) {
    const int idx = it * 256 + tid;
    const int r = idx >> 6, c = idx & 63;
    tile[r][c] = f2bf(w[(size_t)(k0 + r) * N + n0 + c]);
  }
  __syncthreads();
#pragma unroll
  for (int it = 0; it < 16; ++it) {
    const int idx = it * 256 + tid;
    const int r2 = idx >> 6, c2 = idx & 63;
    wt[(size_t)(n0 + r2) * K + k0 + c2] = tile[c2][r2];
  }
}

// ---------------- bf16 GEMM: C[M][N] = A[M][K] * Bt[N][K]^T  (m97 structure) ----------------
template <int OUT_F32>
__global__ __launch_bounds__(256) void gemm_bt(const u16* __restrict__ A, const u16* __restrict__ Bt,
                                               void* __restrict__ Cout, int M, int N, int K) {
  __shared__ u16 As[128 * 32];
  __shared__ u16 Bs[128 * 32];
  const int tid = threadIdx.x;
  const int wave = tid >> 6;
  const int lane = tid & 63;
  const int la = lane & 15, lb = lane >> 4;
  const int m0 = blockIdx.x * 128, n0 = blockIdx.y * 128;
  const int wr = (wave >> 1) * 64, wc = (wave & 1) * 64;
  const int srow = lane >> 2;       // 0..15
  const int scol = (lane & 3) * 8;  // 0,8,16,24
  const int c0 = wave * 2;
  f32x4 acc[4][4] = {};
  for (int k0 = 0; k0 < K; k0 += 32) {
#pragma unroll
    for (int c2 = 0; c2 < 2; ++c2) {
      const int c = c0 + c2;
      const int row = c * 16 + srow;
      gload_lds16(A + (size_t)(m0 + row) * K + k0 + scol, As + c * 512);
      gload_lds16(Bt + (size_t)(n0 + row) * K + k0 + scol, Bs + c * 512);
    }
    __syncthreads();
    bf16x8 af[4], bfr[4];
#pragma unroll
    for (int m = 0; m < 4; ++m) af[m] = *(const bf16x8*)&As[(wr + m * 16 + la) * 32 + lb * 8];
#pragma unroll
    for (int n = 0; n < 4; ++n) bfr[n] = *(const bf16x8*)&Bs[(wc + n * 16 + la) * 32 + lb * 8];
#pragma unroll
    for (int m = 0; m < 4; ++m)
#pragma unroll
      for (int n = 0; n < 4; ++n)
        acc[m][n] = __builtin_amdgcn_mfma_f32_16x16x32_bf16(af[m], bfr[n], acc[m][n], 0, 0, 0);
    __syncthreads();
  }
#pragma unroll
  for (int m = 0; m < 4; ++m)
#pragma unroll
    for (int n = 0; n < 4; ++n)
#pragma unroll
      for (int j = 0; j < 4; ++j) {
        const int row = m0 + wr + m * 16 + lb * 4 + j;
        const int col = n0 + wc + n * 16 + la;
        if (OUT_F32)
          ((float*)Cout)[(size_t)row * N + col] = acc[m][n][j];
        else
          ((u16*)Cout)[(size_t)row * N + col] = f2bf(acc[m][n][j]);
      }
}

// ---------------- RoPE + head reshape + V transpose ----------------
// qkv[b][t][3072] bf16 -> q[bh][t][64] (roped, *0.125*log2e), k[bh][t][64] (roped), vt[bh][64][2048]
__global__ __launch_bounds__(256) void rope_kernel(const u16* __restrict__ QKV, u16* __restrict__ Q,
                                                   u16* __restrict__ K, u16* __restrict__ Vt) {
  const int tt = blockIdx.x * 64;
  const int bh = blockIdx.y;
  const int b = bh >> 4, h = bh & 15;
  const int tid = threadIdx.x;
  __shared__ u16 vtile[64][65];
  const float NEG = -0.41524101186f;  // -log2(10000)/32
  const float QSC = 0.18033688011f;   // 0.125 * log2(e)
#pragma unroll
  for (int it = 0; it < 8; ++it) {
    const int idx = it * 256 + tid;
    const int tl = idx >> 5, i = idx & 31;
    const int t = tt + tl;
    const int d0 = 2 * i;
    const int j0 = d0 & 31, j1 = (d0 + 1) & 31;
    const float a0 = (float)t * exp2f(NEG * (float)j0);
    const float a1 = (float)t * exp2f(NEG * (float)j1);
    float s0, c0v, s1, c1v;
    sincosf(a0, &s0, &c0v);
    sincosf(a1, &s1, &c1v);
    const size_t base = ((size_t)(b * 2048 + t)) * 3072 + h * 64 + d0;
    const size_t ob = ((size_t)bh * 2048 + t) * 64 + d0;
    {
      const float x0 = bf2f(QKV[base]), x1 = bf2f(QKV[base + 1]);
      Q[ob] = f2bf((x0 * c0v - x1 * s0) * QSC);
      Q[ob + 1] = f2bf((x1 * c1v + x0 * s1) * QSC);
    }
    {
      const float x0 = bf2f(QKV[base + 1024]), x1 = bf2f(QKV[base + 1025]);
      K[ob] = f2bf(x0 * c0v - x1 * s0);
      K[ob + 1] = f2bf(x1 * c1v + x0 * s1);
    }
  }
  // V transpose through LDS
#pragma unroll
  for (int it = 0; it < 8; ++it) {
    const int idx = it * 256 + tid;
    const int tl = idx >> 5, d0 = (idx & 31) * 2;
    const size_t base = ((size_t)(b * 2048 + tt + tl)) * 3072 + 2048 + h * 64 + d0;
    vtile[tl][d0] = QKV[base];
    vtile[tl][d0 + 1] = QKV[base + 1];
  }
  __syncthreads();
#pragma unroll
  for (int it = 0; it < 8; ++it) {
    const int idx = it * 256 + tid;
    const int dl = idx >> 5, tp = (idx & 31) * 2;
    const u32 val = (u32)vtile[tp][dl] | ((u32)vtile[tp + 1][dl] << 16);
    *(u32*)(Vt + ((size_t)bh * 64 + dl) * 2048 + tt + tp) = val;
  }
}

// ---------------- flash attention (causal): LDS-staged K/V, mirrored band pairs ----------------
// 512 blocks x 4 waves. Block = bh plane + band pair {B0, 31-B0} (64 rows each).
// Wave w owns 16-row strips at B0*64+16w and (31-B0)*64+16w -> exactly 33 tile-units/wave.
// K/V tiles (64x64 bf16, 8KB each) staged to LDS once per block, double-buffered via
// global_load_lds w=16 with pre-swizzled SOURCE (rule 21); reads XOR-deswizzle (T2).
// XCD swizzle: each XCD owns 4 bh planes entirely (2MB working set < 4MB L2).
__global__ __launch_bounds__(256) void attn_kernel(const u16* __restrict__ Q, const u16* __restrict__ K,
                                                   const u16* __restrict__ Vt, u16* __restrict__ Y) {
  const int L = blockIdx.y * 16 + blockIdx.x;  // 0..511
  const int xcd = L & 7, slot = L >> 3;        // heuristic: linear id % 8 = XCD
  const int bh = xcd * 4 + (slot & 3);
  const int B0 = slot >> 2;                    // 0..15
  const int b = bh >> 4, h = bh & 15;
  const int wave = threadIdx.x >> 6, lane = threadIdx.x & 63;
  const int la = lane & 15, lb = lane >> 4;
  const int NT = 32 - B0;                      // staged kv-tiles per block
  const int ktE0 = B0 + 1;                     // lower strip extent
  const int q0s[2] = {B0 * 64 + wave * 16, (31 - B0) * 64 + wave * 16};

  __shared__ __align__(16) u16 KV[2][2][4096];   // [buf][K/V][64 rows x 64 cols] (swizzled)
  __shared__ __align__(16) u16 Plds[4][2][1152]; // per-wave P staging, stride 72

  const size_t plane = (size_t)bh * (2048 * 64);
  const char* Kb = (const char*)(K + plane);
  const char* Vb = (const char*)(Vt + plane);

  auto stage = [&](int buf, int kt) {
#pragma unroll
    for (int it = 0; it < 2; ++it) {
      const int ci = it * 256 + wave * 64 + lane;        // 16B chunk id 0..511
      const int row = ci >> 3;                           // tile row 0..63
      const int cbs = ((ci & 7) * 16) ^ ((row & 7) << 4);  // pre-swizzled source col byte
      gload_lds16(Kb + (size_t)(kt * 64 + row) * 128 + cbs,
                  (char*)&KV[buf][0][0] + it * 4096 + wave * 1024);
      gload_lds16(Vb + (size_t)row * 4096 + (size_t)kt * 128 + cbs,
                  (char*)&KV[buf][1][0] + it * 4096 + wave * 1024);
    }
  };

  stage(0, 0);

  bf16x8 qf[2][2];
#pragma unroll
  for (int st = 0; st < 2; ++st)
#pragma unroll
    for (int s = 0; s < 2; ++s)
      qf[st][s] = *(const bf16x8*)(Q + plane + (size_t)(q0s[st] + la) * 64 + s * 32 + lb * 8);

  f32x4 o[2][4] = {};
  float mrow[2][4], plr[2][4];
#pragma unroll
  for (int st = 0; st < 2; ++st)
#pragma unroll
    for (int j = 0; j < 4; ++j) {
      mrow[st][j] = -1.0e30f;
      plr[st][j] = 0.f;
    }

  // deswizzled u16 column index within a row, per s (d/t sub-block)
  const int x0 = (la & 7) << 4;
  const int cu0 = ((lb * 16) ^ x0) >> 1;
  const int cu1 = ((64 + lb * 16) ^ x0) >> 1;

  __syncthreads();
  int buf = 0;
  for (int kt = 0; kt < NT; ++kt) {
    if (kt + 1 < NT) stage(buf ^ 1, kt + 1);
    const u16* Kc = KV[buf][0];
    const u16* Vc = KV[buf][1];

    bf16x8 kf[2][4];
#pragma unroll
    for (int n = 0; n < 4; ++n) {
      kf[0][n] = *(const bf16x8*)&Kc[(n * 16 + la) * 64 + cu0];
      kf[1][n] = *(const bf16x8*)&Kc[(n * 16 + la) * 64 + cu1];
    }

    // ---- QK^T + online softmax per strip ----
#pragma unroll
    for (int st = 0; st < 2; ++st) {
      if (st == 0 && kt >= ktE0) continue;
      const int q0 = q0s[st];
      f32x4 sa[4] = {};
#pragma unroll
      for (int s = 0; s < 2; ++s)
#pragma unroll
        for (int n = 0; n < 4; ++n)
          sa[n] = __builtin_amdgcn_mfma_f32_16x16x32_bf16(qf[st][s], kf[s][n], sa[n], 0, 0, 0);
      if (kt * 64 + 63 > q0) {
#pragma unroll
        for (int n = 0; n < 4; ++n)
#pragma unroll
          for (int j = 0; j < 4; ++j) {
            const int row = q0 + lb * 4 + j;
            const int col = kt * 64 + n * 16 + la;
            if (col > row) sa[n][j] = -1.0e30f;
          }
      }
      float lmax[4];
      int need = 0;
#pragma unroll
      for (int j = 0; j < 4; ++j) {
        lmax[j] = fmaxf(fmaxf(sa[0][j], sa[1][j]), fmaxf(sa[2][j], sa[3][j]));
        need |= (lmax[j] > mrow[st][j] + 8.0f);
      }
      if (__any(need)) {
#pragma unroll
        for (int j = 0; j < 4; ++j) {
          float v = lmax[j];
#pragma unroll
          for (int off = 1; off < 16; off <<= 1) v = fmaxf(v, __shfl_xor(v, off));
          const float mn = fmaxf(mrow[st][j], v);
          const float al = __builtin_amdgcn_exp2f(mrow[st][j] - mn);
          plr[st][j] *= al;
#pragma unroll
          for (int n = 0; n < 4; ++n) o[st][n][j] *= al;
          mrow[st][j] = mn;
        }
      }
      u16* pw = &Plds[wave][st][0];
#pragma unroll
      for (int j = 0; j < 4; ++j) {
        float ps = 0.f;
#pragma unroll
        for (int n = 0; n < 4; ++n) {
          const float p = __builtin_amdgcn_exp2f(sa[n][j] - mrow[st][j]);
          ps += p;
          pw[(lb * 4 + j) * 72 + n * 16 + la] = f2bf(p);
        }
        plr[st][j] += ps;
      }
    }

    // ---- PV per strip ----
    bf16x8 vf[2][4];
#pragma unroll
    for (int n = 0; n < 4; ++n) {
      vf[0][n] = *(const bf16x8*)&Vc[(n * 16 + la) * 64 + cu0];
      vf[1][n] = *(const bf16x8*)&Vc[(n * 16 + la) * 64 + cu1];
    }
#pragma unroll
    for (int st = 0; st < 2; ++st) {
      if (st == 0 && kt >= ktE0) continue;
      const u16* pw = &Plds[wave][st][0];
      bf16x8 pf[2];
#pragma unroll
      for (int s = 0; s < 2; ++s) pf[s] = *(const bf16x8*)&pw[la * 72 + s * 32 + lb * 8];
#pragma unroll
      for (int n = 0; n < 4; ++n)
#pragma unroll
        for (int s = 0; s < 2; ++s)
          o[st][n] = __builtin_amdgcn_mfma_f32_16x16x32_bf16(pf[s], vf[s][n], o[st][n], 0, 0, 0);
    }

    __syncthreads();
    buf ^= 1;
  }

  // ---- epilogue: row-sum reduce + scaled write (per wave, no merge) ----
#pragma unroll
  for (int st = 0; st < 2; ++st) {
    float rinv[4];
#pragma unroll
    for (int j = 0; j < 4; ++j) {
      float ls = plr[st][j];
#pragma unroll
      for (int off = 1; off < 16; off <<= 1) ls += __shfl_xor(ls, off);
      rinv[j] = __builtin_amdgcn_rcpf(ls);
    }
#pragma unroll
    for (int n = 0; n < 4; ++n)
#pragma unroll
      for (int j = 0; j < 4; ++j) {
        const int t = q0s[st] + lb * 4 + j;
        const int c = h * 64 + n * 16 + la;
        Y[((size_t)b * 2048 + t) * 1024 + c] = f2bf(o[st][n][j] * rinv[j]);
      }
  }
}

extern "C" void kernel_launch(void* const* d_in, const int* in_sizes, int n_in, void* d_out,
                              int out_size, void* d_ws, size_t ws_size, hipStream_t stream) {
  (void)in_sizes; (void)n_in; (void)out_size; (void)ws_size;
  const float* x = (const float*)d_in[0];
  const float* w_qkv = (const float*)d_in[1];
  const float* w_proj = (const float*)d_in[2];
  char* ws = (char*)d_ws;
  // workspace layout (bytes), total 64 MiB
  u16* xb     = (u16*)(ws);             // 4096*1024 bf16  (8 MiB)  -- reused as y later
  u16* wqkvT  = (u16*)(ws + 8388608);   // 3072*1024       (6 MiB)
  u16* wprojT = (u16*)(ws + 14680064);  // 1024*1024       (2 MiB)
  u16* qkv    = (u16*)(ws + 16777216);  // 4096*3072       (24 MiB)
  u16* q      = (u16*)(ws + 41943040);  // 32*2048*64      (8 MiB)
  u16* k      = (u16*)(ws + 50331648);  // 32*2048*64      (8 MiB)
  u16* vt     = (u16*)(ws + 58720256);  // 32*64*2048      (8 MiB)
  u16* y      = xb;                     // alias: xb dead after GEMM1

  cvt_kernel<<<dim3(4096), dim3(256), 0, stream>>>(x, xb);
  transpose_w<<<dim3(48, 16), dim3(256), 0, stream>>>(w_qkv, wqkvT, 1024, 3072);
  transpose_w<<<dim3(16, 16), dim3(256), 0, stream>>>(w_proj, wprojT, 1024, 1024);
  gemm_bt<0><<<dim3(32, 24), dim3(256), 0, stream>>>(xb, wqkvT, (void*)qkv, 4096, 3072, 1024);
  rope_kernel<<<dim3(32, 32), dim3(256), 0, stream>>>(qkv, q, k, vt);
  attn_kernel<<<dim3(16, 32), dim3(256), 0, stream>>>(q, k, vt, y);
  gemm_bt<1><<<dim3(32, 8), dim3(256), 0, stream>>>(y, wprojT, d_out, 4096, 1024, 1024);
}

// Round 5
// 129.897 us; speedup vs baseline: 2.2097x; 1.0427x over previous
//
#include <hip/hip_runtime.h>
#include <hip/hip_bf16.h>

typedef unsigned short u16;
typedef unsigned int u32;
typedef __attribute__((ext_vector_type(8))) __bf16 bf16x8;
typedef __attribute__((ext_vector_type(4))) float f32x4;
typedef __attribute__((ext_vector_type(4))) u16 u16x4;

__device__ __forceinline__ u16 f2bf(float f) {
  return __builtin_bit_cast(u16, (__bf16)f);  // native RNE cvt
}
__device__ __forceinline__ float bf2f(u16 h) {
  return __builtin_bit_cast(float, (u32)h << 16);
}

__device__ __forceinline__ void gload_lds16(const void* g, void* l) {
  __builtin_amdgcn_global_load_lds((const __attribute__((address_space(1))) void*)g,
                                   (__attribute__((address_space(3))) void*)l, 16, 0, 0);
}

// ---------------- fp32 -> bf16 convert (x) ----------------
__global__ __launch_bounds__(256) void cvt_kernel(const float* __restrict__ in, u16* __restrict__ out) {
  const int i = (blockIdx.x * 256 + threadIdx.x) * 4;
  const float4 v = *(const float4*)(in + i);
  u16x4 r = {f2bf(v.x), f2bf(v.y), f2bf(v.z), f2bf(v.w)};
  *(u16x4*)(out + i) = r;
}

// ---------------- transpose + convert weights: w[K][N] f32 -> wt[N][K] bf16 ----------------
__global__ __launch_bounds__(256) void transpose_w(const float* __restrict__ w, u16* __restrict__ wt,
                                                   int K, int N) {
  __shared__ u16 tile[64][65];
  const int n0 = blockIdx.x * 64, k0 = blockIdx.y * 64;
  const int tid = threadIdx.x;
#pragma unroll
  for (int it = 0; it < 16; ++it) {
    const int idx = it * 256 + tid;
    const int r = idx >> 6, c = idx & 63;
    tile[r][c] = f2bf(w[(size_t)(k0 + r) * N + n0 + c]);
  }
  __syncthreads();
#pragma unroll
  for (int it = 0; it < 16; ++it) {
    const int idx = it * 256 + tid;
    const int r2 = idx >> 6, c2 = idx & 63;
    wt[(size_t)(n0 + r2) * K + k0 + c2] = tile[c2][r2];
  }
}

// ---------------- bf16 GEMM: C[M][N] = A[M][K] * Bt[N][K]^T ----------------
// m97 structure + T3-minimum prefetch double-buffer (stage t+1 before compute t,
// one __syncthreads per K-step = vmcnt(0)+lgkmcnt(0)+barrier) + T1 XCD swizzle.
template <int OUT_F32>
__global__ __launch_bounds__(256) void gemm_bt(const u16* __restrict__ A, const u16* __restrict__ Bt,
                                               void* __restrict__ Cout, int M, int N, int K) {
  __shared__ u16 As[2][128 * 32];
  __shared__ u16 Bs[2][128 * 32];
  const int tid = threadIdx.x;
  const int wave = tid >> 6;
  const int lane = tid & 63;
  const int la = lane & 15, lb = lane >> 4;
  // XCD-chunked bijective swizzle (requires nwg % 8 == 0; 768 and 256 both OK)
  const int nwg = gridDim.x * gridDim.y;
  int lid = blockIdx.y * gridDim.x + blockIdx.x;
  lid = (lid & 7) * (nwg >> 3) + (lid >> 3);
  const int m0 = (lid % gridDim.x) * 128, n0 = (lid / gridDim.x) * 128;
  const int wr = (wave >> 1) * 64, wc = (wave & 1) * 64;
  const int srow = lane >> 2;       // 0..15
  const int scol = (lane & 3) * 8;  // 0,8,16,24
  const int c0 = wave * 2;

  auto stage = [&](int b, int k0) {
#pragma unroll
    for (int c2 = 0; c2 < 2; ++c2) {
      const int c = c0 + c2;
      const int row = c * 16 + srow;
      gload_lds16(A + (size_t)(m0 + row) * K + k0 + scol, As[b] + c * 512);
      gload_lds16(Bt + (size_t)(n0 + row) * K + k0 + scol, Bs[b] + c * 512);
    }
  };

  f32x4 acc[4][4] = {};
  const int nk = K >> 5;
  stage(0, 0);
  __syncthreads();
  int cur = 0;
  for (int t = 0; t < nk; ++t) {
    if (t + 1 < nk) stage(cur ^ 1, (t + 1) * 32);  // prefetch under compute
    bf16x8 af[4], bfr[4];
#pragma unroll
    for (int m = 0; m < 4; ++m) af[m] = *(const bf16x8*)&As[cur][(wr + m * 16 + la) * 32 + lb * 8];
#pragma unroll
    for (int n = 0; n < 4; ++n) bfr[n] = *(const bf16x8*)&Bs[cur][(wc + n * 16 + la) * 32 + lb * 8];
#pragma unroll
    for (int m = 0; m < 4; ++m)
#pragma unroll
      for (int n = 0; n < 4; ++n)
        acc[m][n] = __builtin_amdgcn_mfma_f32_16x16x32_bf16(af[m], bfr[n], acc[m][n], 0, 0, 0);
    __syncthreads();  // drains prefetch vmcnt + guards buffer reuse
    cur ^= 1;
  }
#pragma unroll
  for (int m = 0; m < 4; ++m)
#pragma unroll
    for (int n = 0; n < 4; ++n)
#pragma unroll
      for (int j = 0; j < 4; ++j) {
        const int row = m0 + wr + m * 16 + lb * 4 + j;
        const int col = n0 + wc + n * 16 + la;
        if (OUT_F32)
          ((float*)Cout)[(size_t)row * N + col] = acc[m][n][j];
        else
          ((u16*)Cout)[(size_t)row * N + col] = f2bf(acc[m][n][j]);
      }
}

// ---------------- RoPE + head reshape + V transpose ----------------
// qkv[b][t][3072] bf16 -> q[bh][t][64] (roped, *0.125*log2e), k[bh][t][64] (roped), vt[bh][64][2048]
__global__ __launch_bounds__(256) void rope_kernel(const u16* __restrict__ QKV, u16* __restrict__ Q,
                                                   u16* __restrict__ K, u16* __restrict__ Vt) {
  const int tt = blockIdx.x * 64;
  const int bh = blockIdx.y;
  const int b = bh >> 4, h = bh & 15;
  const int tid = threadIdx.x;
  __shared__ u16 vtile[64][65];
  const float NEG = -0.41524101186f;  // -log2(10000)/32
  const float QSC = 0.18033688011f;   // 0.125 * log2(e)
#pragma unroll
  for (int it = 0; it < 8; ++it) {
    const int idx = it * 256 + tid;
    const int tl = idx >> 5, i = idx & 31;
    const int t = tt + tl;
    const int d0 = 2 * i;
    const int j0 = d0 & 31, j1 = (d0 + 1) & 31;
    const float a0 = (float)t * exp2f(NEG * (float)j0);
    const float a1 = (float)t * exp2f(NEG * (float)j1);
    float s0, c0v, s1, c1v;
    sincosf(a0, &s0, &c0v);
    sincosf(a1, &s1, &c1v);
    const size_t base = ((size_t)(b * 2048 + t)) * 3072 + h * 64 + d0;
    const size_t ob = ((size_t)bh * 2048 + t) * 64 + d0;
    {
      const float x0 = bf2f(QKV[base]), x1 = bf2f(QKV[base + 1]);
      Q[ob] = f2bf((x0 * c0v - x1 * s0) * QSC);
      Q[ob + 1] = f2bf((x1 * c1v + x0 * s1) * QSC);
    }
    {
      const float x0 = bf2f(QKV[base + 1024]), x1 = bf2f(QKV[base + 1025]);
      K[ob] = f2bf(x0 * c0v - x1 * s0);
      K[ob + 1] = f2bf(x1 * c1v + x0 * s1);
    }
  }
  // V transpose through LDS
#pragma unroll
  for (int it = 0; it < 8; ++it) {
    const int idx = it * 256 + tid;
    const int tl = idx >> 5, d0 = (idx & 31) * 2;
    const size_t base = ((size_t)(b * 2048 + tt + tl)) * 3072 + 2048 + h * 64 + d0;
    vtile[tl][d0] = QKV[base];
    vtile[tl][d0 + 1] = QKV[base + 1];
  }
  __syncthreads();
#pragma unroll
  for (int it = 0; it < 8; ++it) {
    const int idx = it * 256 + tid;
    const int dl = idx >> 5, tp = (idx & 31) * 2;
    const u32 val = (u32)vtile[tp][dl] | ((u32)vtile[tp + 1][dl] << 16);
    *(u32*)(Vt + ((size_t)bh * 64 + dl) * 2048 + tt + tp) = val;
  }
}

// ---------------- flash attention (causal): LDS-staged K/V, mirrored band pairs ----------------
__global__ __launch_bounds__(256) void attn_kernel(const u16* __restrict__ Q, const u16* __restrict__ K,
                                                   const u16* __restrict__ Vt, u16* __restrict__ Y) {
  const int L = blockIdx.y * 16 + blockIdx.x;  // 0..511
  const int xcd = L & 7, slot = L >> 3;        // heuristic: linear id % 8 = XCD
  const int bh = xcd * 4 + (slot & 3);
  const int B0 = slot >> 2;                    // 0..15
  const int b = bh >> 4, h = bh & 15;
  const int wave = threadIdx.x >> 6, lane = threadIdx.x & 63;
  const int la = lane & 15, lb = lane >> 4;
  const int NT = 32 - B0;                      // staged kv-tiles per block
  const int ktE0 = B0 + 1;                     // lower strip extent
  const int q0s[2] = {B0 * 64 + wave * 16, (31 - B0) * 64 + wave * 16};

  __shared__ __align__(16) u16 KV[2][2][4096];   // [buf][K/V][64 rows x 64 cols] (swizzled)
  __shared__ __align__(16) u16 Plds[4][2][1152]; // per-wave P staging, stride 72

  const size_t plane = (size_t)bh * (2048 * 64);
  const char* Kb = (const char*)(K + plane);
  const char* Vb = (const char*)(Vt + plane);

  auto stage = [&](int buf, int kt) {
#pragma unroll
    for (int it = 0; it < 2; ++it) {
      const int ci = it * 256 + wave * 64 + lane;          // 16B chunk id 0..511
      const int row = ci >> 3;                             // tile row 0..63
      const int cbs = ((ci & 7) * 16) ^ ((row & 7) << 4);  // pre-swizzled source col byte
      gload_lds16(Kb + (size_t)(kt * 64 + row) * 128 + cbs,
                  (char*)&KV[buf][0][0] + it * 4096 + wave * 1024);
      gload_lds16(Vb + (size_t)row * 4096 + (size_t)kt * 128 + cbs,
                  (char*)&KV[buf][1][0] + it * 4096 + wave * 1024);
    }
  };

  stage(0, 0);

  bf16x8 qf[2][2];
#pragma unroll
  for (int st = 0; st < 2; ++st)
#pragma unroll
    for (int s = 0; s < 2; ++s)
      qf[st][s] = *(const bf16x8*)(Q + plane + (size_t)(q0s[st] + la) * 64 + s * 32 + lb * 8);

  f32x4 o[2][4] = {};
  float mrow[2][4], plr[2][4];
#pragma unroll
  for (int st = 0; st < 2; ++st)
#pragma unroll
    for (int j = 0; j < 4; ++j) {
      mrow[st][j] = -1.0e30f;
      plr[st][j] = 0.f;
    }

  // deswizzled u16 column index within a row, per s (d/t sub-block)
  const int x0 = (la & 7) << 4;
  const int cu0 = ((lb * 16) ^ x0) >> 1;
  const int cu1 = ((64 + lb * 16) ^ x0) >> 1;

  __syncthreads();
  int buf = 0;
  for (int kt = 0; kt < NT; ++kt) {
    if (kt + 1 < NT) stage(buf ^ 1, kt + 1);
    const u16* Kc = KV[buf][0];
    const u16* Vc = KV[buf][1];

    bf16x8 kf[2][4];
#pragma unroll
    for (int n = 0; n < 4; ++n) {
      kf[0][n] = *(const bf16x8*)&Kc[(n * 16 + la) * 64 + cu0];
      kf[1][n] = *(const bf16x8*)&Kc[(n * 16 + la) * 64 + cu1];
    }

    // ---- QK^T + online softmax per strip ----
#pragma unroll
    for (int st = 0; st < 2; ++st) {
      if (st == 0 && kt >= ktE0) continue;
      const int q0 = q0s[st];
      f32x4 sa[4] = {};
      __builtin_amdgcn_s_setprio(1);
#pragma unroll
      for (int s = 0; s < 2; ++s)
#pragma unroll
        for (int n = 0; n < 4; ++n)
          sa[n] = __builtin_amdgcn_mfma_f32_16x16x32_bf16(qf[st][s], kf[s][n], sa[n], 0, 0, 0);
      __builtin_amdgcn_s_setprio(0);
      if (kt * 64 + 63 > q0) {
#pragma unroll
        for (int n = 0; n < 4; ++n)
#pragma unroll
          for (int j = 0; j < 4; ++j) {
            const int row = q0 + lb * 4 + j;
            const int col = kt * 64 + n * 16 + la;
            if (col > row) sa[n][j] = -1.0e30f;
          }
      }
      float lmax[4];
      int need = 0;
#pragma unroll
      for (int j = 0; j < 4; ++j) {
        lmax[j] = fmaxf(fmaxf(sa[0][j], sa[1][j]), fmaxf(sa[2][j], sa[3][j]));
        need |= (lmax[j] > mrow[st][j] + 8.0f);
      }
      if (__any(need)) {
#pragma unroll
        for (int j = 0; j < 4; ++j) {
          float v = lmax[j];
#pragma unroll
          for (int off = 1; off < 16; off <<= 1) v = fmaxf(v, __shfl_xor(v, off));
          const float mn = fmaxf(mrow[st][j], v);
          const float al = __builtin_amdgcn_exp2f(mrow[st][j] - mn);
          plr[st][j] *= al;
#pragma unroll
          for (int n = 0; n < 4; ++n) o[st][n][j] *= al;
          mrow[st][j] = mn;
        }
      }
      u16* pw = &Plds[wave][st][0];
#pragma unroll
      for (int j = 0; j < 4; ++j) {
        float ps = 0.f;
#pragma unroll
        for (int n = 0; n < 4; ++n) {
          const float p = __builtin_amdgcn_exp2f(sa[n][j] - mrow[st][j]);
          ps += p;
          pw[(lb * 4 + j) * 72 + n * 16 + la] = f2bf(p);
        }
        plr[st][j] += ps;
      }
    }

    // ---- PV per strip ----
    bf16x8 vf[2][4];
#pragma unroll
    for (int n = 0; n < 4; ++n) {
      vf[0][n] = *(const bf16x8*)&Vc[(n * 16 + la) * 64 + cu0];
      vf[1][n] = *(const bf16x8*)&Vc[(n * 16 + la) * 64 + cu1];
    }
#pragma unroll
    for (int st = 0; st < 2; ++st) {
      if (st == 0 && kt >= ktE0) continue;
      const u16* pw = &Plds[wave][st][0];
      bf16x8 pf[2];
#pragma unroll
      for (int s = 0; s < 2; ++s) pf[s] = *(const bf16x8*)&pw[la * 72 + s * 32 + lb * 8];
      __builtin_amdgcn_s_setprio(1);
#pragma unroll
      for (int n = 0; n < 4; ++n)
#pragma unroll
        for (int s = 0; s < 2; ++s)
          o[st][n] = __builtin_amdgcn_mfma_f32_16x16x32_bf16(pf[s], vf[s][n], o[st][n], 0, 0, 0);
      __builtin_amdgcn_s_setprio(0);
    }

    __syncthreads();
    buf ^= 1;
  }

  // ---- epilogue: row-sum reduce + scaled write (per wave, no merge) ----
#pragma unroll
  for (int st = 0; st < 2; ++st) {
    float rinv[4];
#pragma unroll
    for (int j = 0; j < 4; ++j) {
      float ls = plr[st][j];
#pragma unroll
      for (int off = 1; off < 16; off <<= 1) ls += __shfl_xor(ls, off);
      rinv[j] = __builtin_amdgcn_rcpf(ls);
    }
#pragma unroll
    for (int n = 0; n < 4; ++n)
#pragma unroll
      for (int j = 0; j < 4; ++j) {
        const int t = q0s[st] + lb * 4 + j;
        const int c = h * 64 + n * 16 + la;
        Y[((size_t)b * 2048 + t) * 1024 + c] = f2bf(o[st][n][j] * rinv[j]);
      }
  }
}

extern "C" void kernel_launch(void* const* d_in, const int* in_sizes, int n_in, void* d_out,
                              int out_size, void* d_ws, size_t ws_size, hipStream_t stream) {
  (void)in_sizes; (void)n_in; (void)out_size; (void)ws_size;
  const float* x = (const float*)d_in[0];
  const float* w_qkv = (const float*)d_in[1];
  const float* w_proj = (const float*)d_in[2];
  char* ws = (char*)d_ws;
  // workspace layout (bytes), total 64 MiB
  u16* xb     = (u16*)(ws);             // 4096*1024 bf16  (8 MiB)  -- reused as y later
  u16* wqkvT  = (u16*)(ws + 8388608);   // 3072*1024       (6 MiB)
  u16* wprojT = (u16*)(ws + 14680064);  // 1024*1024       (2 MiB)
  u16* qkv    = (u16*)(ws + 16777216);  // 4096*3072       (24 MiB)
  u16* q      = (u16*)(ws + 41943040);  // 32*2048*64      (8 MiB)
  u16* k      = (u16*)(ws + 50331648);  // 32*2048*64      (8 MiB)
  u16* vt     = (u16*)(ws + 58720256);  // 32*64*2048      (8 MiB)
  u16* y      = xb;                     // alias: xb dead after GEMM1

  cvt_kernel<<<dim3(4096), dim3(256), 0, stream>>>(x, xb);
  transpose_w<<<dim3(48, 16), dim3(256), 0, stream>>>(w_qkv, wqkvT, 1024, 3072);
  transpose_w<<<dim3(16, 16), dim3(256), 0, stream>>>(w_proj, wprojT, 1024, 1024);
  gemm_bt<0><<<dim3(32, 24), dim3(256), 0, stream>>>(xb, wqkvT, (void*)qkv, 4096, 3072, 1024);
  rope_kernel<<<dim3(32, 32), dim3(256), 0, stream>>>(qkv, q, k, vt);
  attn_kernel<<<dim3(16, 32), dim3(256), 0, stream>>>(q, k, vt, y);
  gemm_bt<1><<<dim3(32, 8), dim3(256), 0, stream>>>(y, wprojT, d_out, 4096, 1024, 1024);
}